// Round 1
// 566.216 us; speedup vs baseline: 1.1050x; 1.1050x over previous
//
#include <hip/hip_runtime.h>
#include <hip/hip_bf16.h>
#include <cstdint>
#include <cstddef>

#define NPIX 4096   // H*W = 64*64
#define CIN  256
#define CQK  32
#define BSZ  4

typedef __attribute__((ext_vector_type(8))) short          bf16x8;
typedef __attribute__((ext_vector_type(4))) float          f32x4;
typedef __attribute__((ext_vector_type(8))) unsigned short u16x8;

static __device__ inline unsigned short f2bf(float f) {
    __hip_bfloat16 h = __float2bfloat16(f);   // RNE
    unsigned short u;
    __builtin_memcpy(&u, &h, 2);
    return u;
}

static __device__ inline void gl2lds16(const void* g, void* l) {
    // 16B-per-lane direct global->LDS; LDS dest is wave-uniform base + lane*16
    __builtin_amdgcn_global_load_lds(
        (const __attribute__((address_space(1))) unsigned int*)g,
        (__attribute__((address_space(3))) unsigned int*)l,
        16, 0, 0);
}

// ---------------- Kernel 1 (fallback only): fp32 projection ----------------
__global__ __launch_bounds__(256) void proj_kernel(
    const float* __restrict__ x, const float* __restrict__ W,
    const float* __restrict__ bias, float* __restrict__ y, int Cout)
{
    __shared__ float Wl[8][CIN];
    const int t  = threadIdx.x;
    const int n0 = blockIdx.x * 1024;
    const int o0 = blockIdx.y * 8;
    const int b  = blockIdx.z;

    #pragma unroll
    for (int j = 0; j < 8; ++j) {
        int flat = t + 256 * j;
        int row = flat >> 8, col = flat & 255;
        Wl[row][col] = W[(o0 + row) * CIN + col];
    }
    __syncthreads();

    float acc[8][4];
    #pragma unroll
    for (int o = 0; o < 8; ++o)
        #pragma unroll
        for (int i = 0; i < 4; ++i) acc[o][i] = 0.f;

    const float* xb = x + ((size_t)b * CIN) * NPIX + n0 + t * 4;
    #pragma unroll 4
    for (int c = 0; c < CIN; ++c) {
        float4 xv = *(const float4*)(xb + (size_t)c * NPIX);
        #pragma unroll
        for (int o = 0; o < 8; ++o) {
            float w = Wl[o][c];
            acc[o][0] = fmaf(w, xv.x, acc[o][0]);
            acc[o][1] = fmaf(w, xv.y, acc[o][1]);
            acc[o][2] = fmaf(w, xv.z, acc[o][2]);
            acc[o][3] = fmaf(w, xv.w, acc[o][3]);
        }
    }
    #pragma unroll
    for (int o = 0; o < 8; ++o) {
        float bb = bias[o0 + o];
        float4 r = { acc[o][0] + bb, acc[o][1] + bb,
                     acc[o][2] + bb, acc[o][3] + bb };
        *(float4*)(y + ((size_t)(b * Cout + o0 + o)) * NPIX + n0 + t * 4) = r;
    }
}

// ---------------- Kernel 1a: fused q+k projection (fp32 out) ---------------
// grid (8, 8, B): blockIdx.y selects 8 of the 64 combined {q,k} output rows.
__global__ __launch_bounds__(256) void proj_qk_kernel(
    const float* __restrict__ x,
    const float* __restrict__ wq, const float* __restrict__ bq,
    const float* __restrict__ wk, const float* __restrict__ bk,
    float* __restrict__ qout, float* __restrict__ kout)
{
    __shared__ float Wl[CIN][12];   // [c][o], padded: 48B row, 16B-aligned
    const int t  = threadIdx.x;
    const int n0 = blockIdx.x * 512;
    const int og = blockIdx.y * 8;
    const int b  = blockIdx.z;
    const bool isK = og >= CQK;               // block-uniform
    const float* W    = isK ? wk : wq;
    const float* bias = isK ? bk : bq;
    float* y          = isK ? kout : qout;
    const int o0      = isK ? og - CQK : og;

    #pragma unroll
    for (int j = 0; j < 8; ++j) {
        int flat = t + 256 * j;
        int o = flat >> 8, c = flat & 255;
        Wl[c][o] = W[(o0 + o) * CIN + c];
    }
    __syncthreads();

    float acc[8][2];
    #pragma unroll
    for (int o = 0; o < 8; ++o) { acc[o][0] = 0.f; acc[o][1] = 0.f; }

    const float* xb = x + ((size_t)b * CIN) * NPIX + n0 + t * 2;
    #pragma unroll 4
    for (int c = 0; c < CIN; ++c) {
        float2 xv = *(const float2*)(xb + (size_t)c * NPIX);
        f32x4 w0 = *(const f32x4*)&Wl[c][0];   // lane-uniform: LDS broadcast
        f32x4 w1 = *(const f32x4*)&Wl[c][4];
        float wv[8] = { w0[0], w0[1], w0[2], w0[3],
                        w1[0], w1[1], w1[2], w1[3] };
        #pragma unroll
        for (int o = 0; o < 8; ++o) {
            acc[o][0] = fmaf(wv[o], xv.x, acc[o][0]);
            acc[o][1] = fmaf(wv[o], xv.y, acc[o][1]);
        }
    }
    #pragma unroll
    for (int o = 0; o < 8; ++o) {
        float bb = bias[o0 + o];
        float2 r = { acc[o][0] + bb, acc[o][1] + bb };
        *(float2*)(y + ((size_t)(b * CQK + o0 + o)) * NPIX + n0 + t * 2) = r;
    }
}

// ---------------- Kernel 1b: v projection, bf16 out ------------------------
// 16 outputs x 512 px per block -> 512 blocks, x re-read 16x (was 32x).
__global__ __launch_bounds__(256) void proj_v_bf16_kernel(
    const float* __restrict__ x, const float* __restrict__ W,
    const float* __restrict__ bias, unsigned short* __restrict__ y)
{
    __shared__ float Wl[CIN][20];   // [c][o], padded: 80B row, 16B-aligned
    const int t  = threadIdx.x;
    const int n0 = blockIdx.x * 512;
    const int o0 = blockIdx.y * 16;
    const int b  = blockIdx.z;

    #pragma unroll
    for (int j = 0; j < 16; ++j) {
        int flat = t + 256 * j;
        int o = flat >> 8, c = flat & 255;
        Wl[c][o] = W[(o0 + o) * CIN + c];
    }
    __syncthreads();

    float acc[16][2];
    #pragma unroll
    for (int o = 0; o < 16; ++o) { acc[o][0] = 0.f; acc[o][1] = 0.f; }

    const float* xb = x + ((size_t)b * CIN) * NPIX + n0 + t * 2;
    #pragma unroll 2
    for (int c = 0; c < CIN; ++c) {
        float2 xv = *(const float2*)(xb + (size_t)c * NPIX);
        f32x4 w0 = *(const f32x4*)&Wl[c][0];
        f32x4 w1 = *(const f32x4*)&Wl[c][4];
        f32x4 w2 = *(const f32x4*)&Wl[c][8];
        f32x4 w3 = *(const f32x4*)&Wl[c][12];
        float wv[16] = { w0[0], w0[1], w0[2], w0[3],
                         w1[0], w1[1], w1[2], w1[3],
                         w2[0], w2[1], w2[2], w2[3],
                         w3[0], w3[1], w3[2], w3[3] };
        #pragma unroll
        for (int o = 0; o < 16; ++o) {
            acc[o][0] = fmaf(wv[o], xv.x, acc[o][0]);
            acc[o][1] = fmaf(wv[o], xv.y, acc[o][1]);
        }
    }
    #pragma unroll
    for (int o = 0; o < 16; ++o) {
        float bb = bias[o0 + o];
        ushort2 r;
        r.x = f2bf(acc[o][0] + bb);
        r.y = f2bf(acc[o][1] + bb);
        *(ushort2*)(y + ((size_t)(b * CIN + o0 + o)) * NPIX + n0 + t * 2) = r;
    }
}

// ---------------- Kernel 2: energy + softmax (fused) -----------------------
// 2 block barriers total (was 32); k-vector via ds_read_b128 broadcast;
// at_map stores are non-temporal (never re-read; keep attn_bf L3-resident).
__global__ __launch_bounds__(512) void energy_softmax_kernel(
    const float* __restrict__ q, const float* __restrict__ k,
    float* __restrict__ at_map, unsigned short* __restrict__ attn_bf)
{
    __shared__ float kk[CQK][12];   // [c][mi], padded to keep 16B alignment
    __shared__ float wredM[8][8];   // [mi][wave]
    __shared__ float wredS[8][8];
    const int t  = threadIdx.x;
    const int m0 = blockIdx.x * 8;
    const int b  = blockIdx.y;
    const int lane = t & 63, wid = t >> 6;

    if (t < 256) {
        int c = t >> 3, mi = t & 7;
        kk[c][mi] = k[((size_t)(b * CQK + c)) * NPIX + m0 + mi];
    }
    __syncthreads();

    float s[8][8];
    #pragma unroll
    for (int mi = 0; mi < 8; ++mi)
        #pragma unroll
        for (int i = 0; i < 8; ++i) s[mi][i] = 0.f;

    const float* qb = q + ((size_t)b * CQK) * NPIX + t * 8;
    #pragma unroll 2
    for (int c = 0; c < CQK; ++c) {
        float4 q0 = *(const float4*)(qb + (size_t)c * NPIX);
        float4 q1 = *(const float4*)(qb + (size_t)c * NPIX + 4);
        f32x4 k0 = *(const f32x4*)&kk[c][0];   // lane-uniform broadcast
        f32x4 k1 = *(const f32x4*)&kk[c][4];
        float kv[8] = { k0[0], k0[1], k0[2], k0[3],
                        k1[0], k1[1], k1[2], k1[3] };
        #pragma unroll
        for (int mi = 0; mi < 8; ++mi) {
            float w = kv[mi];
            s[mi][0] = fmaf(w, q0.x, s[mi][0]);
            s[mi][1] = fmaf(w, q0.y, s[mi][1]);
            s[mi][2] = fmaf(w, q0.z, s[mi][2]);
            s[mi][3] = fmaf(w, q0.w, s[mi][3]);
            s[mi][4] = fmaf(w, q1.x, s[mi][4]);
            s[mi][5] = fmaf(w, q1.y, s[mi][5]);
            s[mi][6] = fmaf(w, q1.z, s[mi][6]);
            s[mi][7] = fmaf(w, q1.w, s[mi][7]);
        }
    }

    // ---- phase 1: per-wave max for all 8 rows, ONE barrier ----
    #pragma unroll
    for (int mi = 0; mi < 8; ++mi) {
        float mx = s[mi][0];
        #pragma unroll
        for (int i = 1; i < 8; ++i) mx = fmaxf(mx, s[mi][i]);
        #pragma unroll
        for (int off = 1; off < 64; off <<= 1)
            mx = fmaxf(mx, __shfl_xor(mx, off, 64));
        if (lane == 0) wredM[mi][wid] = mx;
    }
    __syncthreads();

    // ---- phase 2: exp + per-wave sum for all 8 rows, ONE barrier ----
    #pragma unroll
    for (int mi = 0; mi < 8; ++mi) {
        float bmx = wredM[mi][0];
        #pragma unroll
        for (int w = 1; w < 8; ++w) bmx = fmaxf(bmx, wredM[mi][w]);
        float sum = 0.f;
        #pragma unroll
        for (int i = 0; i < 8; ++i) {
            s[mi][i] = __expf(s[mi][i] - bmx);
            sum += s[mi][i];
        }
        #pragma unroll
        for (int off = 1; off < 64; off <<= 1)
            sum += __shfl_xor(sum, off, 64);
        if (lane == 0) wredS[mi][wid] = sum;
    }
    __syncthreads();

    // ---- phase 3: normalize + write ----
    #pragma unroll
    for (int mi = 0; mi < 8; ++mi) {
        float bsum = 0.f;
        #pragma unroll
        for (int w = 0; w < 8; ++w) bsum += wredS[mi][w];
        float inv = 1.f / bsum;
        size_t rowoff = ((size_t)(b * NPIX) + m0 + mi) * NPIX + t * 8;
        float a0 = s[mi][0]*inv, a1 = s[mi][1]*inv, a2 = s[mi][2]*inv, a3 = s[mi][3]*inv;
        float a4 = s[mi][4]*inv, a5 = s[mi][5]*inv, a6 = s[mi][6]*inv, a7 = s[mi][7]*inv;
        f32x4 r0 = { a0, a1, a2, a3 };
        f32x4 r1 = { a4, a5, a6, a7 };
        __builtin_nontemporal_store(r0, (f32x4*)(at_map + rowoff));
        __builtin_nontemporal_store(r1, (f32x4*)(at_map + rowoff + 4));
        if (attn_bf) {
            u16x8 rb;
            rb[0] = f2bf(a0); rb[1] = f2bf(a1); rb[2] = f2bf(a2); rb[3] = f2bf(a3);
            rb[4] = f2bf(a4); rb[5] = f2bf(a5); rb[6] = f2bf(a6); rb[7] = f2bf(a7);
            *(u16x8*)(attn_bf + rowoff) = rb;
        }
    }
}

// ---------------- Kernel 3 (fast): sa = V*attn^T via bf16 MFMA -------------
// O[c,m] = sum_n V[c,n]*attn[m,n]; both operands K-major (n contiguous).
// 128(c) x 64(m) block tile, BK=64 -> grid (64,2,B) = 512 blocks = 2/CU
// (was 256 = 1 wave/SIMD -> latency-starved barrier drains).
// 4 waves, each 64(c)x32(m) = 4x2 frags of mfma_f32_16x16x32_bf16.
// XOR granule swizzle (granule ^ row&7): ds_read_b128 2 lanes/bank (free).
__global__ __launch_bounds__(256) void sa_gemm_mfma(
    const unsigned short* __restrict__ v,     // [B,CIN,N] bf16
    const unsigned short* __restrict__ attn,  // [B,N,N]  bf16
    const float* __restrict__ x, const float* __restrict__ gptr,
    float* __restrict__ out)
{
    __shared__ __align__(16) unsigned short As[128 * 64];  // 16 KB (c x k)
    __shared__ __align__(16) unsigned short Bs[64 * 64];   //  8 KB (m x k)

    const int t = threadIdx.x, lane = t & 63, w = t >> 6;
    const int m_base = blockIdx.x * 64;
    const int c_base = blockIdx.y * 128;
    const int b      = blockIdx.z;
    const int wc = (w >> 1) * 64, wm = (w & 1) * 32;

    // ---- staging lane mapping: 8 rows x 8 granules(16B) per instruction ----
    const int lrow = lane >> 3;            // row within 8-row group
    const int glog = (lane & 7) ^ lrow;    // swizzled logical granule
    const unsigned short* aSrc[4];
    const unsigned short* bSrc[2];
    #pragma unroll
    for (int qi = 0; qi < 4; ++qi)
        aSrc[qi] = v    + ((size_t)(b * CIN + c_base + w * 32 + qi * 8 + lrow)) * NPIX + glog * 8;
    #pragma unroll
    for (int qi = 0; qi < 2; ++qi)
        bSrc[qi] = attn + ((size_t)b * NPIX + m_base + w * 16 + qi * 8 + lrow) * NPIX + glog * 8;

    // ---- compute lane mapping ----
    const int l15 = lane & 15, q4 = lane >> 4;
    const int x0 = (q4 ^ (lane & 7)) * 8;          // kstep0 swizzled elem off
    const int x1 = ((q4 ^ 4) ^ (lane & 7)) * 8;    // kstep1
    const int baseA = (wc + l15) * 64;
    const int baseB = (wm + l15) * 64;

    f32x4 acc[4][2];
    #pragma unroll
    for (int i = 0; i < 4; ++i)
        #pragma unroll
        for (int j = 0; j < 2; ++j) acc[i][j] = (f32x4)(0.0f);

    for (int k0 = 0; k0 < NPIX; k0 += 64) {
        #pragma unroll
        for (int qi = 0; qi < 4; ++qi)
            gl2lds16(aSrc[qi] + k0, &As[(w * 32 + qi * 8) * 64]);
        #pragma unroll
        for (int qi = 0; qi < 2; ++qi)
            gl2lds16(bSrc[qi] + k0, &Bs[(w * 16 + qi * 8) * 64]);
        __syncthreads();
        #pragma unroll
        for (int ks = 0; ks < 2; ++ks) {
            const int xo = ks ? x1 : x0;
            bf16x8 af[4], bfr[2];
            #pragma unroll
            for (int i = 0; i < 4; ++i)
                af[i] = *(const bf16x8*)&As[baseA + i * 1024 + xo];
            #pragma unroll
            for (int j = 0; j < 2; ++j)
                bfr[j] = *(const bf16x8*)&Bs[baseB + j * 1024 + xo];
            #pragma unroll
            for (int i = 0; i < 4; ++i)
                #pragma unroll
                for (int j = 0; j < 2; ++j)
                    acc[i][j] = __builtin_amdgcn_mfma_f32_16x16x32_bf16(
                        af[i], bfr[j], acc[i][j], 0, 0, 0);
        }
        __syncthreads();
    }

    // ---- epilogue: out = x + gamma*sa.  D: row=(lane>>4)*4+r, col=lane&15 --
    const float g = gptr[0];
    #pragma unroll
    for (int i = 0; i < 4; ++i) {
        int c = c_base + wc + i * 16 + q4 * 4;
        #pragma unroll
        for (int j = 0; j < 2; ++j) {
            int m = m_base + wm + j * 16 + l15;
            #pragma unroll
            for (int r = 0; r < 4; ++r) {
                size_t idx = ((size_t)(b * CIN + c + r)) * NPIX + m;
                float val = x[idx] + g * acc[i][j][r];
                __builtin_nontemporal_store(val, &out[idx]);
            }
        }
    }
}

// ---------------- Kernel 3 (fallback): fp32 VALU GEMM ----------------------
__global__ __launch_bounds__(256) void sa_gemm_kernel(
    const float* __restrict__ v, const float* __restrict__ at_map,
    const float* __restrict__ x, const float* __restrict__ gptr,
    float* __restrict__ out)
{
    __shared__ float Vt[32][68];
    __shared__ float At[32][68];
    const int t  = threadIdx.x;
    const int m0 = blockIdx.x * 64;
    const int c0 = blockIdx.y * 64;
    const int b  = blockIdx.z;
    const int r  = t >> 2, qd = t & 3;
    const int tc = t & 15, tm = t >> 4;

    const float* vb = v      + ((size_t)(b * CIN  + c0 + r)) * NPIX + qd * 4;
    const float* ab = at_map + ((size_t)(b * NPIX + m0 + r)) * NPIX + qd * 4;

    float acc[4][4];
    #pragma unroll
    for (int i = 0; i < 4; ++i)
        #pragma unroll
        for (int j = 0; j < 4; ++j) acc[i][j] = 0.f;

    for (int n0 = 0; n0 < NPIX; n0 += 32) {
        float4 v0 = *(const float4*)(vb + n0);
        float4 v1 = *(const float4*)(vb + n0 + 16);
        float4 a0 = *(const float4*)(ab + n0);
        float4 a1 = *(const float4*)(ab + n0 + 16);
        Vt[qd*4+0][r] = v0.x; Vt[qd*4+1][r] = v0.y;
        Vt[qd*4+2][r] = v0.z; Vt[qd*4+3][r] = v0.w;
        Vt[16+qd*4+0][r] = v1.x; Vt[16+qd*4+1][r] = v1.y;
        Vt[16+qd*4+2][r] = v1.z; Vt[16+qd*4+3][r] = v1.w;
        At[qd*4+0][r] = a0.x; At[qd*4+1][r] = a0.y;
        At[qd*4+2][r] = a0.z; At[qd*4+3][r] = a0.w;
        At[16+qd*4+0][r] = a1.x; At[16+qd*4+1][r] = a1.y;
        At[16+qd*4+2][r] = a1.z; At[16+qd*4+3][r] = a1.w;
        __syncthreads();
        #pragma unroll
        for (int kk = 0; kk < 32; ++kk) {
            float4 a  = *(const float4*)&Vt[kk][tc * 4];
            float4 bb = *(const float4*)&At[kk][tm * 4];
            acc[0][0] = fmaf(a.x, bb.x, acc[0][0]);
            acc[0][1] = fmaf(a.x, bb.y, acc[0][1]);
            acc[0][2] = fmaf(a.x, bb.z, acc[0][2]);
            acc[0][3] = fmaf(a.x, bb.w, acc[0][3]);
            acc[1][0] = fmaf(a.y, bb.x, acc[1][0]);
            acc[1][1] = fmaf(a.y, bb.y, acc[1][1]);
            acc[1][2] = fmaf(a.y, bb.z, acc[1][2]);
            acc[1][3] = fmaf(a.y, bb.w, acc[1][3]);
            acc[2][0] = fmaf(a.z, bb.x, acc[2][0]);
            acc[2][1] = fmaf(a.z, bb.y, acc[2][1]);
            acc[2][2] = fmaf(a.z, bb.z, acc[2][2]);
            acc[2][3] = fmaf(a.z, bb.w, acc[2][3]);
            acc[3][0] = fmaf(a.w, bb.x, acc[3][0]);
            acc[3][1] = fmaf(a.w, bb.y, acc[3][1]);
            acc[3][2] = fmaf(a.w, bb.z, acc[3][2]);
            acc[3][3] = fmaf(a.w, bb.w, acc[3][3]);
        }
        __syncthreads();
    }

    const float g = *gptr;
    #pragma unroll
    for (int i = 0; i < 4; ++i) {
        size_t row = ((size_t)(b * CIN + c0 + tc * 4 + i)) * NPIX + m0 + tm * 4;
        float4 xv = *(const float4*)(x + row);
        float4 o  = { xv.x + g * acc[i][0], xv.y + g * acc[i][1],
                      xv.z + g * acc[i][2], xv.w + g * acc[i][3] };
        *(float4*)(out + row) = o;
    }
}

extern "C" void kernel_launch(void* const* d_in, const int* in_sizes, int n_in,
                              void* d_out, int out_size, void* d_ws, size_t ws_size,
                              hipStream_t stream) {
    const float* x     = (const float*)d_in[0];
    const float* wq    = (const float*)d_in[1];
    const float* bq    = (const float*)d_in[2];
    const float* wk    = (const float*)d_in[3];
    const float* bk    = (const float*)d_in[4];
    const float* wv    = (const float*)d_in[5];
    const float* bv    = (const float*)d_in[6];
    const float* gamma = (const float*)d_in[7];

    float* out    = (float*)d_out;                   // [B,C,H,W]
    float* at_map = out + (size_t)BSZ * CIN * NPIX;  // [B,N,N] fp32

    const size_t qk_elems  = (size_t)BSZ * CQK * NPIX;   // 524288
    const size_t v_elems   = (size_t)BSZ * CIN * NPIX;   // 4194304
    const size_t nn_elems  = (size_t)BSZ * NPIX * NPIX;  // 67108864

    // fast path needs: q,k fp32 + v bf16 + attn bf16
    const size_t need_fast = 2 * qk_elems * 4 + v_elems * 2 + nn_elems * 2;

    if (ws_size >= need_fast) {
        float*          q       = (float*)d_ws;
        float*          k       = q + qk_elems;
        unsigned short* v_bf    = (unsigned short*)(k + qk_elems);
        unsigned short* attn_bf = v_bf + v_elems;

        proj_qk_kernel<<<dim3(NPIX/512, 8, BSZ), 256, 0, stream>>>(
            x, wq, bq, wk, bk, q, k);
        proj_v_bf16_kernel<<<dim3(NPIX/512, CIN/16, BSZ), 256, 0, stream>>>(
            x, wv, bv, v_bf);

        energy_softmax_kernel<<<dim3(NPIX/8, BSZ), 512, 0, stream>>>(q, k, at_map, attn_bf);

        sa_gemm_mfma<<<dim3(NPIX/64, CIN/128, BSZ), 256, 0, stream>>>(
            v_bf, attn_bf, x, gamma, out);
    } else {
        // fallback: all-fp32 path
        float* q = (float*)d_ws;
        float* k = q + qk_elems;
        float* v = k + qk_elems;

        proj_kernel<<<dim3(NPIX/1024, CQK/8, BSZ), 256, 0, stream>>>(x, wq, bq, q, CQK);
        proj_kernel<<<dim3(NPIX/1024, CQK/8, BSZ), 256, 0, stream>>>(x, wk, bk, k, CQK);
        proj_kernel<<<dim3(NPIX/1024, CIN/8, BSZ), 256, 0, stream>>>(x, wv, bv, v, CIN);

        energy_softmax_kernel<<<dim3(NPIX/8, BSZ), 512, 0, stream>>>(q, k, at_map, nullptr);

        sa_gemm_kernel<<<dim3(NPIX/64, CIN/64, BSZ), 256, 0, stream>>>(
            v, at_map, x, gamma, out);
    }
}

// Round 2
// 539.702 us; speedup vs baseline: 1.1593x; 1.0491x over previous
//
#include <hip/hip_runtime.h>
#include <hip/hip_bf16.h>
#include <cstdint>
#include <cstddef>

#define NPIX 4096   // H*W = 64*64
#define CIN  256
#define CQK  32
#define BSZ  4

typedef __attribute__((ext_vector_type(8))) short          bf16x8;
typedef __attribute__((ext_vector_type(4))) float          f32x4;
typedef __attribute__((ext_vector_type(8))) unsigned short u16x8;

static __device__ inline unsigned short f2bf(float f) {
    __hip_bfloat16 h = __float2bfloat16(f);   // RNE
    unsigned short u;
    __builtin_memcpy(&u, &h, 2);
    return u;
}

static __device__ inline void gl2lds16(const void* g, void* l) {
    // 16B-per-lane direct global->LDS; LDS dest is wave-uniform base + lane*16
    __builtin_amdgcn_global_load_lds(
        (const __attribute__((address_space(1))) unsigned int*)g,
        (__attribute__((address_space(3))) unsigned int*)l,
        16, 0, 0);
}

// ---------------- Kernel 1 (fallback only): fp32 projection ----------------
__global__ __launch_bounds__(256) void proj_kernel(
    const float* __restrict__ x, const float* __restrict__ W,
    const float* __restrict__ bias, float* __restrict__ y, int Cout)
{
    __shared__ float Wl[8][CIN];
    const int t  = threadIdx.x;
    const int n0 = blockIdx.x * 1024;
    const int o0 = blockIdx.y * 8;
    const int b  = blockIdx.z;

    #pragma unroll
    for (int j = 0; j < 8; ++j) {
        int flat = t + 256 * j;
        int row = flat >> 8, col = flat & 255;
        Wl[row][col] = W[(o0 + row) * CIN + col];
    }
    __syncthreads();

    float acc[8][4];
    #pragma unroll
    for (int o = 0; o < 8; ++o)
        #pragma unroll
        for (int i = 0; i < 4; ++i) acc[o][i] = 0.f;

    const float* xb = x + ((size_t)b * CIN) * NPIX + n0 + t * 4;
    #pragma unroll 4
    for (int c = 0; c < CIN; ++c) {
        float4 xv = *(const float4*)(xb + (size_t)c * NPIX);
        #pragma unroll
        for (int o = 0; o < 8; ++o) {
            float w = Wl[o][c];
            acc[o][0] = fmaf(w, xv.x, acc[o][0]);
            acc[o][1] = fmaf(w, xv.y, acc[o][1]);
            acc[o][2] = fmaf(w, xv.z, acc[o][2]);
            acc[o][3] = fmaf(w, xv.w, acc[o][3]);
        }
    }
    #pragma unroll
    for (int o = 0; o < 8; ++o) {
        float bb = bias[o0 + o];
        float4 r = { acc[o][0] + bb, acc[o][1] + bb,
                     acc[o][2] + bb, acc[o][3] + bb };
        *(float4*)(y + ((size_t)(b * Cout + o0 + o)) * NPIX + n0 + t * 4) = r;
    }
}

// ---------------- Kernel 1a: fused q+k projection (fp32 out) ---------------
__global__ __launch_bounds__(256) void proj_qk_kernel(
    const float* __restrict__ x,
    const float* __restrict__ wq, const float* __restrict__ bq,
    const float* __restrict__ wk, const float* __restrict__ bk,
    float* __restrict__ qout, float* __restrict__ kout)
{
    __shared__ float Wl[CIN][12];   // [c][o], padded: 48B row, 16B-aligned
    const int t  = threadIdx.x;
    const int n0 = blockIdx.x * 512;
    const int og = blockIdx.y * 8;
    const int b  = blockIdx.z;
    const bool isK = og >= CQK;               // block-uniform
    const float* W    = isK ? wk : wq;
    const float* bias = isK ? bk : bq;
    float* y          = isK ? kout : qout;
    const int o0      = isK ? og - CQK : og;

    #pragma unroll
    for (int j = 0; j < 8; ++j) {
        int flat = t + 256 * j;
        int o = flat >> 8, c = flat & 255;
        Wl[c][o] = W[(o0 + o) * CIN + c];
    }
    __syncthreads();

    float acc[8][2];
    #pragma unroll
    for (int o = 0; o < 8; ++o) { acc[o][0] = 0.f; acc[o][1] = 0.f; }

    const float* xb = x + ((size_t)b * CIN) * NPIX + n0 + t * 2;
    #pragma unroll 4
    for (int c = 0; c < CIN; ++c) {
        float2 xv = *(const float2*)(xb + (size_t)c * NPIX);
        f32x4 w0 = *(const f32x4*)&Wl[c][0];   // lane-uniform: LDS broadcast
        f32x4 w1 = *(const f32x4*)&Wl[c][4];
        float wv[8] = { w0[0], w0[1], w0[2], w0[3],
                        w1[0], w1[1], w1[2], w1[3] };
        #pragma unroll
        for (int o = 0; o < 8; ++o) {
            acc[o][0] = fmaf(wv[o], xv.x, acc[o][0]);
            acc[o][1] = fmaf(wv[o], xv.y, acc[o][1]);
        }
    }
    #pragma unroll
    for (int o = 0; o < 8; ++o) {
        float bb = bias[o0 + o];
        float2 r = { acc[o][0] + bb, acc[o][1] + bb };
        *(float2*)(y + ((size_t)(b * CQK + o0 + o)) * NPIX + n0 + t * 2) = r;
    }
}

// ---------------- Kernel 1b: v projection, bf16 out ------------------------
__global__ __launch_bounds__(256) void proj_v_bf16_kernel(
    const float* __restrict__ x, const float* __restrict__ W,
    const float* __restrict__ bias, unsigned short* __restrict__ y)
{
    __shared__ float Wl[CIN][20];   // [c][o], padded: 80B row, 16B-aligned
    const int t  = threadIdx.x;
    const int n0 = blockIdx.x * 512;
    const int o0 = blockIdx.y * 16;
    const int b  = blockIdx.z;

    #pragma unroll
    for (int j = 0; j < 16; ++j) {
        int flat = t + 256 * j;
        int o = flat >> 8, c = flat & 255;
        Wl[c][o] = W[(o0 + o) * CIN + c];
    }
    __syncthreads();

    float acc[16][2];
    #pragma unroll
    for (int o = 0; o < 16; ++o) { acc[o][0] = 0.f; acc[o][1] = 0.f; }

    const float* xb = x + ((size_t)b * CIN) * NPIX + n0 + t * 2;
    #pragma unroll 2
    for (int c = 0; c < CIN; ++c) {
        float2 xv = *(const float2*)(xb + (size_t)c * NPIX);
        f32x4 w0 = *(const f32x4*)&Wl[c][0];
        f32x4 w1 = *(const f32x4*)&Wl[c][4];
        f32x4 w2 = *(const f32x4*)&Wl[c][8];
        f32x4 w3 = *(const f32x4*)&Wl[c][12];
        float wv[16] = { w0[0], w0[1], w0[2], w0[3],
                         w1[0], w1[1], w1[2], w1[3],
                         w2[0], w2[1], w2[2], w2[3],
                         w3[0], w3[1], w3[2], w3[3] };
        #pragma unroll
        for (int o = 0; o < 16; ++o) {
            acc[o][0] = fmaf(wv[o], xv.x, acc[o][0]);
            acc[o][1] = fmaf(wv[o], xv.y, acc[o][1]);
        }
    }
    #pragma unroll
    for (int o = 0; o < 16; ++o) {
        float bb = bias[o0 + o];
        ushort2 r;
        r.x = f2bf(acc[o][0] + bb);
        r.y = f2bf(acc[o][1] + bb);
        *(ushort2*)(y + ((size_t)(b * CIN + o0 + o)) * NPIX + n0 + t * 2) = r;
    }
}

// ---------------- Kernel 2: energy + softmax (fused) -----------------------
// 2 block barriers; plain cached stores (NT 16B stores showed 1.5x HBM write
// amplification last round: 613 MB vs 402 MB ideal).  bf16 attn is stored
// UNNORMALIZED in phase 2 (overlaps reduction); per-row 1/sum goes to inv_buf
// and the MFMA GEMM applies it in its epilogue.
__global__ __launch_bounds__(512) void energy_softmax_kernel(
    const float* __restrict__ q, const float* __restrict__ k,
    float* __restrict__ at_map, unsigned short* __restrict__ attn_bf,
    float* __restrict__ inv_buf)
{
    __shared__ float kk[CQK][12];   // [c][mi], padded to keep 16B alignment
    __shared__ float wredM[8][8];   // [mi][wave]
    __shared__ float wredS[8][8];
    const int t  = threadIdx.x;
    const int m0 = blockIdx.x * 8;
    const int b  = blockIdx.y;
    const int lane = t & 63, wid = t >> 6;

    if (t < 256) {
        int c = t >> 3, mi = t & 7;
        kk[c][mi] = k[((size_t)(b * CQK + c)) * NPIX + m0 + mi];
    }
    __syncthreads();

    float s[8][8];
    #pragma unroll
    for (int mi = 0; mi < 8; ++mi)
        #pragma unroll
        for (int i = 0; i < 8; ++i) s[mi][i] = 0.f;

    const float* qb = q + ((size_t)b * CQK) * NPIX + t * 8;
    #pragma unroll 2
    for (int c = 0; c < CQK; ++c) {
        float4 q0 = *(const float4*)(qb + (size_t)c * NPIX);
        float4 q1 = *(const float4*)(qb + (size_t)c * NPIX + 4);
        f32x4 k0 = *(const f32x4*)&kk[c][0];   // lane-uniform broadcast
        f32x4 k1 = *(const f32x4*)&kk[c][4];
        float kv[8] = { k0[0], k0[1], k0[2], k0[3],
                        k1[0], k1[1], k1[2], k1[3] };
        #pragma unroll
        for (int mi = 0; mi < 8; ++mi) {
            float w = kv[mi];
            s[mi][0] = fmaf(w, q0.x, s[mi][0]);
            s[mi][1] = fmaf(w, q0.y, s[mi][1]);
            s[mi][2] = fmaf(w, q0.z, s[mi][2]);
            s[mi][3] = fmaf(w, q0.w, s[mi][3]);
            s[mi][4] = fmaf(w, q1.x, s[mi][4]);
            s[mi][5] = fmaf(w, q1.y, s[mi][5]);
            s[mi][6] = fmaf(w, q1.z, s[mi][6]);
            s[mi][7] = fmaf(w, q1.w, s[mi][7]);
        }
    }

    // ---- phase 1: per-wave max for all 8 rows, ONE barrier ----
    #pragma unroll
    for (int mi = 0; mi < 8; ++mi) {
        float mx = s[mi][0];
        #pragma unroll
        for (int i = 1; i < 8; ++i) mx = fmaxf(mx, s[mi][i]);
        #pragma unroll
        for (int off = 1; off < 64; off <<= 1)
            mx = fmaxf(mx, __shfl_xor(mx, off, 64));
        if (lane == 0) wredM[mi][wid] = mx;
    }
    __syncthreads();

    // ---- phase 2: exp; store UNNORMALIZED bf16 p early; per-wave sum ----
    #pragma unroll
    for (int mi = 0; mi < 8; ++mi) {
        float bmx = wredM[mi][0];
        #pragma unroll
        for (int w = 1; w < 8; ++w) bmx = fmaxf(bmx, wredM[mi][w]);
        float sum = 0.f;
        #pragma unroll
        for (int i = 0; i < 8; ++i) {
            s[mi][i] = __expf(s[mi][i] - bmx);
            sum += s[mi][i];
        }
        if (attn_bf) {
            size_t rowoff = ((size_t)(b * NPIX) + m0 + mi) * NPIX + t * 8;
            u16x8 rb;
            #pragma unroll
            for (int i = 0; i < 8; ++i) rb[i] = f2bf(s[mi][i]);
            *(u16x8*)(attn_bf + rowoff) = rb;
        }
        #pragma unroll
        for (int off = 1; off < 64; off <<= 1)
            sum += __shfl_xor(sum, off, 64);
        if (lane == 0) wredS[mi][wid] = sum;
    }
    __syncthreads();

    // ---- phase 3: normalize + write fp32 at_map (+ inv for the GEMM) ----
    #pragma unroll
    for (int mi = 0; mi < 8; ++mi) {
        float bsum = 0.f;
        #pragma unroll
        for (int w = 0; w < 8; ++w) bsum += wredS[mi][w];
        float inv = 1.f / bsum;
        if (inv_buf && t == mi) inv_buf[(size_t)b * NPIX + m0 + mi] = inv;
        size_t rowoff = ((size_t)(b * NPIX) + m0 + mi) * NPIX + t * 8;
        float4 r0 = { s[mi][0]*inv, s[mi][1]*inv, s[mi][2]*inv, s[mi][3]*inv };
        float4 r1 = { s[mi][4]*inv, s[mi][5]*inv, s[mi][6]*inv, s[mi][7]*inv };
        *(float4*)(at_map + rowoff)     = r0;
        *(float4*)(at_map + rowoff + 4) = r1;
    }
}

// ---------------- Kernel 3 (fast): sa = V*attn^T via bf16 MFMA -------------
// O[c,m] = inv[m] * sum_n V[c,n]*p[m,n]; both operands K-major.
// 128(c) x 64(m) tile, BK=64, grid flat 512 with bijective XCD remap:
// per XCD, c-tiles of the same m are adjacent (attn panel L2-reused) and
// both 1MB v panels stay L2-resident.  4 waves, 64(c)x32(m) each.
__global__ __launch_bounds__(256) void sa_gemm_mfma(
    const unsigned short* __restrict__ v,     // [B,CIN,N] bf16
    const unsigned short* __restrict__ attn,  // [B,N,N]  bf16 (unnormalized p)
    const float* __restrict__ x, const float* __restrict__ gptr,
    const float* __restrict__ inv_buf,        // [B,N] 1/rowsum
    float* __restrict__ out)
{
    __shared__ __align__(16) unsigned short As[128 * 64];  // 16 KB (c x k)
    __shared__ __align__(16) unsigned short Bs[64 * 64];   //  8 KB (m x k)

    const int t = threadIdx.x, lane = t & 63, w = t >> 6;

    // ---- bijective XCD-aware decode (512 blocks, 64 per XCD) ----
    const int gid  = blockIdx.x;
    const int xcd  = gid & 7;
    const int slot = gid >> 3;            // 0..63
    const int c_t     = slot & 1;         // c-tiles adjacent -> L2 reuse
    const int m_local = (slot >> 1) & 7;
    const int b       = slot >> 4;        // 0..3
    const int m_base = (xcd * 8 + m_local) * 64;
    const int c_base = c_t * 128;
    const int wc = (w >> 1) * 64, wm = (w & 1) * 32;

    // ---- staging lane mapping: 8 rows x 8 granules(16B) per instruction ----
    const int lrow = lane >> 3;            // row within 8-row group
    const int glog = (lane & 7) ^ lrow;    // swizzled logical granule
    const unsigned short* aSrc[4];
    const unsigned short* bSrc[2];
    #pragma unroll
    for (int qi = 0; qi < 4; ++qi)
        aSrc[qi] = v    + ((size_t)(b * CIN + c_base + w * 32 + qi * 8 + lrow)) * NPIX + glog * 8;
    #pragma unroll
    for (int qi = 0; qi < 2; ++qi)
        bSrc[qi] = attn + ((size_t)b * NPIX + m_base + w * 16 + qi * 8 + lrow) * NPIX + glog * 8;

    // ---- compute lane mapping ----
    const int l15 = lane & 15, q4 = lane >> 4;
    const int x0 = (q4 ^ (lane & 7)) * 8;          // kstep0 swizzled elem off
    const int x1 = ((q4 ^ 4) ^ (lane & 7)) * 8;    // kstep1
    const int baseA = (wc + l15) * 64;
    const int baseB = (wm + l15) * 64;

    f32x4 acc[4][2];
    #pragma unroll
    for (int i = 0; i < 4; ++i)
        #pragma unroll
        for (int j = 0; j < 2; ++j) acc[i][j] = (f32x4)(0.0f);

    for (int k0 = 0; k0 < NPIX; k0 += 64) {
        #pragma unroll
        for (int qi = 0; qi < 4; ++qi)
            gl2lds16(aSrc[qi] + k0, &As[(w * 32 + qi * 8) * 64]);
        #pragma unroll
        for (int qi = 0; qi < 2; ++qi)
            gl2lds16(bSrc[qi] + k0, &Bs[(w * 16 + qi * 8) * 64]);
        __syncthreads();
        #pragma unroll
        for (int ks = 0; ks < 2; ++ks) {
            const int xo = ks ? x1 : x0;
            bf16x8 af[4], bfr[2];
            #pragma unroll
            for (int i = 0; i < 4; ++i)
                af[i] = *(const bf16x8*)&As[baseA + i * 1024 + xo];
            #pragma unroll
            for (int j = 0; j < 2; ++j)
                bfr[j] = *(const bf16x8*)&Bs[baseB + j * 1024 + xo];
            #pragma unroll
            for (int i = 0; i < 4; ++i)
                #pragma unroll
                for (int j = 0; j < 2; ++j)
                    acc[i][j] = __builtin_amdgcn_mfma_f32_16x16x32_bf16(
                        af[i], bfr[j], acc[i][j], 0, 0, 0);
        }
        __syncthreads();
    }

    // ---- epilogue: out = x + gamma*inv[m]*sa.  D: row=(q4)*4+r, col=l15 ----
    const float g = gptr[0];
    float invm[2];
    #pragma unroll
    for (int j = 0; j < 2; ++j)
        invm[j] = inv_buf[(size_t)b * NPIX + m_base + wm + j * 16 + l15];
    #pragma unroll
    for (int i = 0; i < 4; ++i) {
        int c = c_base + wc + i * 16 + q4 * 4;
        #pragma unroll
        for (int j = 0; j < 2; ++j) {
            int m = m_base + wm + j * 16 + l15;
            float gi = g * invm[j];
            #pragma unroll
            for (int r = 0; r < 4; ++r) {
                size_t idx = ((size_t)(b * CIN + c + r)) * NPIX + m;
                out[idx] = x[idx] + gi * acc[i][j][r];
            }
        }
    }
}

// ---------------- Kernel 3 (fallback): fp32 VALU GEMM ----------------------
__global__ __launch_bounds__(256) void sa_gemm_kernel(
    const float* __restrict__ v, const float* __restrict__ at_map,
    const float* __restrict__ x, const float* __restrict__ gptr,
    float* __restrict__ out)
{
    __shared__ float Vt[32][68];
    __shared__ float At[32][68];
    const int t  = threadIdx.x;
    const int m0 = blockIdx.x * 64;
    const int c0 = blockIdx.y * 64;
    const int b  = blockIdx.z;
    const int r  = t >> 2, qd = t & 3;
    const int tc = t & 15, tm = t >> 4;

    const float* vb = v      + ((size_t)(b * CIN  + c0 + r)) * NPIX + qd * 4;
    const float* ab = at_map + ((size_t)(b * NPIX + m0 + r)) * NPIX + qd * 4;

    float acc[4][4];
    #pragma unroll
    for (int i = 0; i < 4; ++i)
        #pragma unroll
        for (int j = 0; j < 4; ++j) acc[i][j] = 0.f;

    for (int n0 = 0; n0 < NPIX; n0 += 32) {
        float4 v0 = *(const float4*)(vb + n0);
        float4 v1 = *(const float4*)(vb + n0 + 16);
        float4 a0 = *(const float4*)(ab + n0);
        float4 a1 = *(const float4*)(ab + n0 + 16);
        Vt[qd*4+0][r] = v0.x; Vt[qd*4+1][r] = v0.y;
        Vt[qd*4+2][r] = v0.z; Vt[qd*4+3][r] = v0.w;
        Vt[16+qd*4+0][r] = v1.x; Vt[16+qd*4+1][r] = v1.y;
        Vt[16+qd*4+2][r] = v1.z; Vt[16+qd*4+3][r] = v1.w;
        At[qd*4+0][r] = a0.x; At[qd*4+1][r] = a0.y;
        At[qd*4+2][r] = a0.z; At[qd*4+3][r] = a0.w;
        At[16+qd*4+0][r] = a1.x; At[16+qd*4+1][r] = a1.y;
        At[16+qd*4+2][r] = a1.z; At[16+qd*4+3][r] = a1.w;
        __syncthreads();
        #pragma unroll
        for (int kk = 0; kk < 32; ++kk) {
            float4 a  = *(const float4*)&Vt[kk][tc * 4];
            float4 bb = *(const float4*)&At[kk][tm * 4];
            acc[0][0] = fmaf(a.x, bb.x, acc[0][0]);
            acc[0][1] = fmaf(a.x, bb.y, acc[0][1]);
            acc[0][2] = fmaf(a.x, bb.z, acc[0][2]);
            acc[0][3] = fmaf(a.x, bb.w, acc[0][3]);
            acc[1][0] = fmaf(a.y, bb.x, acc[1][0]);
            acc[1][1] = fmaf(a.y, bb.y, acc[1][1]);
            acc[1][2] = fmaf(a.y, bb.z, acc[1][2]);
            acc[1][3] = fmaf(a.y, bb.w, acc[1][3]);
            acc[2][0] = fmaf(a.z, bb.x, acc[2][0]);
            acc[2][1] = fmaf(a.z, bb.y, acc[2][1]);
            acc[2][2] = fmaf(a.z, bb.z, acc[2][2]);
            acc[2][3] = fmaf(a.z, bb.w, acc[2][3]);
            acc[3][0] = fmaf(a.w, bb.x, acc[3][0]);
            acc[3][1] = fmaf(a.w, bb.y, acc[3][1]);
            acc[3][2] = fmaf(a.w, bb.z, acc[3][2]);
            acc[3][3] = fmaf(a.w, bb.w, acc[3][3]);
        }
        __syncthreads();
    }

    const float g = *gptr;
    #pragma unroll
    for (int i = 0; i < 4; ++i) {
        size_t row = ((size_t)(b * CIN + c0 + tc * 4 + i)) * NPIX + m0 + tm * 4;
        float4 xv = *(const float4*)(x + row);
        float4 o  = { xv.x + g * acc[i][0], xv.y + g * acc[i][1],
                      xv.z + g * acc[i][2], xv.w + g * acc[i][3] };
        *(float4*)(out + row) = o;
    }
}

extern "C" void kernel_launch(void* const* d_in, const int* in_sizes, int n_in,
                              void* d_out, int out_size, void* d_ws, size_t ws_size,
                              hipStream_t stream) {
    const float* x     = (const float*)d_in[0];
    const float* wq    = (const float*)d_in[1];
    const float* bq    = (const float*)d_in[2];
    const float* wk    = (const float*)d_in[3];
    const float* bk    = (const float*)d_in[4];
    const float* wv    = (const float*)d_in[5];
    const float* bv    = (const float*)d_in[6];
    const float* gamma = (const float*)d_in[7];

    float* out    = (float*)d_out;                   // [B,C,H,W]
    float* at_map = out + (size_t)BSZ * CIN * NPIX;  // [B,N,N] fp32

    const size_t qk_elems  = (size_t)BSZ * CQK * NPIX;   // 524288
    const size_t v_elems   = (size_t)BSZ * CIN * NPIX;   // 4194304
    const size_t nn_elems  = (size_t)BSZ * NPIX * NPIX;  // 67108864
    const size_t inv_elems = (size_t)BSZ * NPIX;         // 16384

    // fast path needs: q,k fp32 + v bf16 + attn bf16 + inv fp32
    const size_t need_fast = 2 * qk_elems * 4 + v_elems * 2 + nn_elems * 2
                           + inv_elems * 4;

    if (ws_size >= need_fast) {
        float*          q       = (float*)d_ws;
        float*          k       = q + qk_elems;
        unsigned short* v_bf    = (unsigned short*)(k + qk_elems);
        unsigned short* attn_bf = v_bf + v_elems;
        float*          inv_buf = (float*)(attn_bf + nn_elems);

        proj_qk_kernel<<<dim3(NPIX/512, 8, BSZ), 256, 0, stream>>>(
            x, wq, bq, wk, bk, q, k);
        proj_v_bf16_kernel<<<dim3(NPIX/512, CIN/16, BSZ), 256, 0, stream>>>(
            x, wv, bv, v_bf);

        energy_softmax_kernel<<<dim3(NPIX/8, BSZ), 512, 0, stream>>>(
            q, k, at_map, attn_bf, inv_buf);

        sa_gemm_mfma<<<dim3(512, 1, 1), 256, 0, stream>>>(
            v_bf, attn_bf, x, gamma, inv_buf, out);
    } else {
        // fallback: all-fp32 path
        float* q = (float*)d_ws;
        float* k = q + qk_elems;
        float* v = k + qk_elems;

        proj_kernel<<<dim3(NPIX/1024, CQK/8, BSZ), 256, 0, stream>>>(x, wq, bq, q, CQK);
        proj_kernel<<<dim3(NPIX/1024, CQK/8, BSZ), 256, 0, stream>>>(x, wk, bk, k, CQK);
        proj_kernel<<<dim3(NPIX/1024, CIN/8, BSZ), 256, 0, stream>>>(x, wv, bv, v, CIN);

        energy_softmax_kernel<<<dim3(NPIX/8, BSZ), 512, 0, stream>>>(
            q, k, at_map, nullptr, nullptr);

        sa_gemm_kernel<<<dim3(NPIX/64, CIN/64, BSZ), 256, 0, stream>>>(
            v, at_map, x, gamma, out);
    }
}